// Round 3
// baseline (755.323 us; speedup 1.0000x reference)
//
#include <hip/hip_runtime.h>

#define B_SZ   4096
#define D_SZ   128
#define K_SZ   256
#define N_ROWS 1000000
#define RSHIFT 6                       // 64 rows per bucket (32 KB region)
#define ROWS   (1 << RSHIFT)
#define NBUCK  16384                   // >= ceil(1e6/64) = 15625
#define NB_USED 15625
#define BCAP   256                     // avg 67 entries, +23 sigma headroom
#define LDS_PITCH 132                  // 128 + 4 floats: breaks bank aliasing

constexpr float INV_T    = 1.0f / 0.07f;
constexpr float NOISE    = 255.0f / 1000000.0f;   // (K-1)/N
constexpr float EPS_C    = 1e-7f;
constexpr float K_OVER_N = 256.0f / 1000000.0f;   // K/N

// ---------------------------------------------------------------------------
// ws layout: [cnt: 64 KB][ent: NBUCK*BCAP*8 = 32 MB][esims: 4 MB][partial]
// ---------------------------------------------------------------------------

__global__ __launch_bounds__(256) void zero_counters(int* __restrict__ cnt)
{
    const int i = blockIdx.x * 256 + threadIdx.x;
    if (i < NBUCK) cnt[i] = 0;
}

// entry = (row << 32) | i   with i = b*256+k  (also the esims index)
__global__ __launch_bounds__(256, 8) void bin_samples(
    const int* __restrict__ targets,
    const int* __restrict__ indices,
    int*                 __restrict__ cnt,
    unsigned long long*  __restrict__ ent)
{
    const int i = blockIdx.x * 256 + threadIdx.x;   // i < B*K
    const int b = i >> 8;
    const int k = i & (K_SZ - 1);
    const int row = (k == 0) ? targets[b] : indices[i];
    const int bu  = row >> RSHIFT;
    const int slot = atomicAdd(&cnt[bu], 1);
    if (slot < BCAP)
        ent[(size_t)bu * BCAP + slot] =
            ((unsigned long long)(unsigned)row << 32) | (unsigned)i;
}

// One block per 64-row region of `memory`.
// Phase 1: stream the whole 32 KB region into LDS, fully coalesced --
//          DRAM sees ONLY sequential sweeps of the memory bank.
// Phase 2: dot each binned sample against its row in LDS (8 lanes/entry),
//          x[b] comes from global (2 MB, L2-resident), scatter exp(logit).
__global__ __launch_bounds__(256, 4) void gather_dot(
    const float* __restrict__ x,        // [B, D]
    const float* __restrict__ memory,   // [N, D]
    const int*                __restrict__ cnt,
    const unsigned long long* __restrict__ ent,
    float*       __restrict__ esims)    // [B*K]
{
    __shared__ float s_mem[ROWS * LDS_PITCH];   // 33,792 B -> 4 blocks/CU

    const int bu = blockIdx.x;
    const int nb = min(cnt[bu], BCAP);

    const int row0  = bu << RSHIFT;
    const int nrows = min(ROWS, N_ROWS - row0);
    const int tid   = threadIdx.x;

    if (nb > 0) {
        // ---- phase 1: sequential region sweep -> LDS (padded rows) ----
        const float4* __restrict__ src =
            (const float4*)(memory + (size_t)row0 * D_SZ);
        const int nchunk = nrows * (D_SZ / 4);           // float4 count
        for (int idx = tid; idx < nchunk; idx += 256) {
            const int r = idx >> 5;                      // row in region
            const int c = idx & 31;                      // float4 slot
            const float4 v = src[idx];                   // coalesced
            *(float4*)&s_mem[r * LDS_PITCH + c * 4] = v;
        }
    }
    __syncthreads();
    if (nb == 0) return;

    // ---- phase 2: 8 lanes per entry, 32 entries per round ----
    const int g = tid >> 3;      // entry group 0..31
    const int s = tid & 7;       // float4 slot within 128 B chunk

    for (int base = 0; base < nb; base += 32) {
        const int e  = base + g;
        const int ec = min(e, nb - 1);                   // keep reads valid
        const unsigned long long pk = ent[(size_t)bu * BCAP + ec];
        const int i    = (int)(pk & 0xffffffffu);
        const int rloc = ((int)(pk >> 32)) & (ROWS - 1);

        const float* __restrict__ rp = &s_mem[rloc * LDS_PITCH + s * 4];
        const float4* __restrict__ xp =
            (const float4*)(x + (size_t)(i >> 8) * D_SZ) + s;

        const float4 r0 = *(const float4*)(rp + 0);
        const float4 r1 = *(const float4*)(rp + 32);
        const float4 r2 = *(const float4*)(rp + 64);
        const float4 r3 = *(const float4*)(rp + 96);
        const float4 x0 = xp[0];
        const float4 x1 = xp[8];
        const float4 x2 = xp[16];
        const float4 x3 = xp[24];

        float a0 = 0.f, a1 = 0.f;
        a0 = fmaf(r0.x, x0.x, fmaf(r0.y, x0.y, fmaf(r0.z, x0.z, fmaf(r0.w, x0.w, a0))));
        a1 = fmaf(r1.x, x1.x, fmaf(r1.y, x1.y, fmaf(r1.z, x1.z, fmaf(r1.w, x1.w, a1))));
        a0 = fmaf(r2.x, x2.x, fmaf(r2.y, x2.y, fmaf(r2.z, x2.z, fmaf(r2.w, x2.w, a0))));
        a1 = fmaf(r3.x, x3.x, fmaf(r3.y, x3.y, fmaf(r3.z, x3.z, fmaf(r3.w, x3.w, a1))));
        float p = a0 + a1;

        p += __shfl_xor(p, 1, 64);
        p += __shfl_xor(p, 2, 64);
        p += __shfl_xor(p, 4, 64);

        if (s == 0 && e < nb)
            esims[i] = expf(p * INV_T);    // 4 MB region: L2 absorbs scatter
    }
}

// Per batch-row softmax denominator + NCE loss terms.
__global__ __launch_bounds__(256, 8) void reduce_loss(
    const float* __restrict__ esims,    // [B*K]
    float*       __restrict__ partial)  // [B]
{
    __shared__ float s_red[4];
    const int b    = blockIdx.x;
    const int tid  = threadIdx.x;
    const int lane = tid & 63;
    const int wave = tid >> 6;

    const float e = esims[(size_t)b * K_SZ + tid];

    float sum = e;
    #pragma unroll
    for (int m = 32; m >= 1; m >>= 1)
        sum += __shfl_xor(sum, m, 64);
    if (lane == 0) s_red[wave] = sum;
    __syncthreads();
    const float S = s_red[0] + s_red[1] + s_red[2] + s_red[3];

    const float sims = e * (K_OVER_N / S);
    float term = (tid == 0)
        ? logf(sims / (sims + NOISE + EPS_C))    // lnPmt (positive)
        : logf(NOISE / (sims + NOISE + EPS_C));  // lnPon (noise)

    #pragma unroll
    for (int m = 32; m >= 1; m >>= 1)
        term += __shfl_xor(term, m, 64);
    __syncthreads();
    if (lane == 0) s_red[wave] = term;
    __syncthreads();
    if (tid == 0)
        partial[b] = s_red[0] + s_red[1] + s_red[2] + s_red[3];
}

__global__ __launch_bounds__(256) void nce_final(
    const float* __restrict__ partial, float* __restrict__ out)
{
    const int tid = threadIdx.x;
    float s = 0.0f;
    #pragma unroll
    for (int i = tid; i < B_SZ; i += 256)
        s += partial[i];
    #pragma unroll
    for (int m = 32; m >= 1; m >>= 1)
        s += __shfl_xor(s, m, 64);
    __shared__ float sr[4];
    if ((tid & 63) == 0) sr[tid >> 6] = s;
    __syncthreads();
    if (tid == 0)
        out[0] = -(sr[0] + sr[1] + sr[2] + sr[3]) / (float)B_SZ;
}

extern "C" void kernel_launch(void* const* d_in, const int* in_sizes, int n_in,
                              void* d_out, int out_size, void* d_ws, size_t ws_size,
                              hipStream_t stream) {
    const float* x       = (const float*)d_in[0];
    const int*   targets = (const int*)  d_in[1];
    const float* memory  = (const float*)d_in[2];
    const int*   indices = (const int*)  d_in[3];
    float* out = (float*)d_out;

    char* ws = (char*)d_ws;
    int*                cnt     = (int*)ws;                          // 64 KB
    unsigned long long* ent     = (unsigned long long*)(ws + 65536); // 32 MB
    float*              esims   = (float*)(ws + 65536 + (size_t)NBUCK * BCAP * 8);
    float*              partial = esims + (size_t)B_SZ * K_SZ;

    zero_counters<<<NBUCK / 256, 256, 0, stream>>>(cnt);
    bin_samples<<<(B_SZ * K_SZ) / 256, 256, 0, stream>>>(targets, indices, cnt, ent);
    gather_dot<<<NB_USED, 256, 0, stream>>>(x, memory, cnt, ent, esims);
    reduce_loss<<<B_SZ, 256, 0, stream>>>(esims, partial);
    nce_final<<<1, 256, 0, stream>>>(partial, out);
}

// Round 4
// 638.744 us; speedup vs baseline: 1.1825x; 1.1825x over previous
//
#include <hip/hip_runtime.h>

#define B_SZ 4096
#define D_SZ 128
#define K_SZ 256

constexpr float INV_T    = 1.0f / 0.07f;
constexpr float NOISE    = 255.0f / 1000000.0f;   // (K-1)/N
constexpr float EPS_C    = 1e-7f;
constexpr float K_OVER_N = 256.0f / 1000000.0f;   // K/N

// r0 structure (best known: 643 us) + one change: each wave visits its 64
// sampled rows in ASCENDING row order via an in-register bitonic sort.
// All waves run in loose lockstep, so the chip-wide request stream becomes
// a rolling address sweep over `memory`:
//   - duplicate rows (1.6x sample/row ratio) cluster in time -> L3 absorbs
//     the reuse even though the 333 MB distinct set overflows 256 MB L3
//   - per-channel DRAM streams become near-monotonic -> page-hit friendly
// Output is bitwise identical to r0: only the iteration order of
// independent samples changes; s_e[] lands at the same slots.
__global__ __launch_bounds__(256, 8) void nce_main(
    const float* __restrict__ x,        // [B, D]
    const int*   __restrict__ targets,  // [B]
    const float* __restrict__ memory,   // [N, D]
    const int*   __restrict__ indices,  // [B, K]
    float*       __restrict__ partial)  // [B]
{
    __shared__ float s_e[K_SZ];
    __shared__ float s_red[4];

    const int b    = blockIdx.x;
    const int tid  = threadIdx.x;
    const int lane = tid & 63;
    const int wave = tid >> 6;
    const int sub  = lane & 31;   // float4 slot within the row
    const int half = lane >> 5;   // which of the 2 rows this lane serves

    // lane covers x[b, 4*sub .. 4*sub+3]
    const float4 xv = ((const float4*)(x + (size_t)b * D_SZ))[sub];

    // this lane's sample (col 0 overwritten with the positive target)
    const int row0 = (tid == 0) ? targets[b]
                                : indices[(size_t)b * K_SZ + tid];

    // pack (row, lane): row<2^20 fits in bits 8..27, lane in bits 0..5.
    unsigned key = ((unsigned)row0 << 8) | (unsigned)lane;

    // 64-lane bitonic sort, ascending by row (21 shfl_xor exchanges, once).
    #pragma unroll
    for (int k = 2; k <= 64; k <<= 1) {
        #pragma unroll
        for (int j = k >> 1; j > 0; j >>= 1) {
            const unsigned other = __shfl_xor(key, j, 64);
            const bool keepMin = (((lane & k) == 0) == ((lane & j) == 0));
            key = keepMin ? (key < other ? key : other)
                          : (key > other ? key : other);
        }
    }

    #pragma unroll 4
    for (int it = 0; it < 32; ++it) {
        const int kk = it * 2 + half;
        const unsigned v = __shfl(key, kk, 64);   // broadcast sorted entry
        const int row = (int)(v >> 8);
        const int kl  = (int)(v & 63u);           // original lane = k within wave
        const float4 wv = ((const float4*)(memory + (size_t)row * D_SZ))[sub];
        float p = fmaf(wv.x, xv.x, fmaf(wv.y, xv.y,
                  fmaf(wv.z, xv.z, wv.w * xv.w)));
        // reduce within each 32-lane half (masks < 32 never cross halves)
        #pragma unroll
        for (int m = 16; m >= 1; m >>= 1)
            p += __shfl_xor(p, m, 64);
        if (sub == 0)
            s_e[wave * 64 + kl] = expf(p * INV_T);
    }
    __syncthreads();

    // block reduce: S = sum_k exp(logit_k)
    const float e = s_e[tid];
    float sum = e;
    #pragma unroll
    for (int m = 32; m >= 1; m >>= 1)
        sum += __shfl_xor(sum, m, 64);
    if (lane == 0) s_red[wave] = sum;
    __syncthreads();
    const float S = s_red[0] + s_red[1] + s_red[2] + s_red[3];

    // sims_k = e_k / S * (K/N)
    const float sims = e * (K_OVER_N / S);
    float term;
    if (tid == 0)
        term = logf(sims / (sims + NOISE + EPS_C));   // lnPmt (positive)
    else
        term = logf(NOISE / (sims + NOISE + EPS_C));  // lnPon (noise)

    float t = term;
    #pragma unroll
    for (int m = 32; m >= 1; m >>= 1)
        t += __shfl_xor(t, m, 64);
    __syncthreads();   // all reads of s_red done before re-use
    if (lane == 0) s_red[wave] = t;
    __syncthreads();
    if (tid == 0)
        partial[b] = s_red[0] + s_red[1] + s_red[2] + s_red[3];
}

// Single-block reduction of the 4096 per-row partials.
__global__ __launch_bounds__(256) void nce_final(
    const float* __restrict__ partial, float* __restrict__ out)
{
    const int tid = threadIdx.x;
    float s = 0.0f;
    #pragma unroll
    for (int i = tid; i < B_SZ; i += 256)
        s += partial[i];
    #pragma unroll
    for (int m = 32; m >= 1; m >>= 1)
        s += __shfl_xor(s, m, 64);
    __shared__ float sr[4];
    if ((tid & 63) == 0) sr[tid >> 6] = s;
    __syncthreads();
    if (tid == 0)
        out[0] = -(sr[0] + sr[1] + sr[2] + sr[3]) / (float)B_SZ;
}

extern "C" void kernel_launch(void* const* d_in, const int* in_sizes, int n_in,
                              void* d_out, int out_size, void* d_ws, size_t ws_size,
                              hipStream_t stream) {
    const float* x       = (const float*)d_in[0];
    const int*   targets = (const int*)  d_in[1];
    const float* memory  = (const float*)d_in[2];
    const int*   indices = (const int*)  d_in[3];
    float* out     = (float*)d_out;
    float* partial = (float*)d_ws;   // B floats of scratch

    nce_main<<<B_SZ, 256, 0, stream>>>(x, targets, memory, indices, partial);
    nce_final<<<1, 256, 0, stream>>>(partial, out);
}